// Round 1
// baseline (134.156 us; speedup 1.0000x reference)
//
#include <hip/hip_runtime.h>
#include <hip/hip_bf16.h>

#define NB 1024
#define NH 256
#define EMB 128
#define TWOD 256
#define HID 256

typedef __attribute__((ext_vector_type(4))) float f32x4;
typedef __attribute__((ext_vector_type(8))) short bf16x8;

__device__ __forceinline__ unsigned short f2bf(float f) {
  union { float f; unsigned u; } v; v.f = f;
  unsigned u = v.u;
  unsigned r = (u + 0x7fffu + ((u >> 16) & 1u)) >> 16;
  return (unsigned short)r;
}

// W1 [d=256][n=256] fp32  ->  W1T [n][d] bf16 (B-fragment layout: n-major, k contiguous)
__global__ __launch_bounds__(256) void prep_w1t(const float* __restrict__ W1,
                                                unsigned short* __restrict__ W1T) {
  const int d = blockIdx.x;   // 0..255  (input dim = k)
  const int n = threadIdx.x;  // 0..255  (hidden col)
  W1T[(size_t)n * TWOD + d] = f2bf(W1[(size_t)d * HID + n]);
}

// tgtv[b][0..255] = concat(E_targ[target[b]], E_reg[tregion[b]])
__global__ __launch_bounds__(256) void prep_tgt(const int* __restrict__ target,
                                                const int* __restrict__ tregion,
                                                const float* __restrict__ E_targ,
                                                const float* __restrict__ E_reg,
                                                float* __restrict__ tgtv) {
  const int b = blockIdx.x;
  const int c = threadIdx.x;
  float v = (c < EMB) ? E_targ[(size_t)target[b] * EMB + c]
                      : E_reg[(size_t)tregion[b] * EMB + (c - EMB)];
  tgtv[(size_t)b * TWOD + c] = v;
}

// One block per batch element b. 256 threads = 4 waves.
// Per chunk of 64 history rows:
//   build inp = (hist ⊙ tgt) bf16 tile in LDS (swizzled), dot_ht = row-sum (fp32)
//   each wave: 64x64 output strip of hid = relu(inp@W1 + b1), score += hid·w2
//   wave 0: masked exp, accumulate denom and numerator; final sigmoid.
__global__ __launch_bounds__(256) void nais_main(
    const int* __restrict__ history, const int* __restrict__ target,
    const int* __restrict__ hregion,
    const float* __restrict__ E_hist, const float* __restrict__ E_reg,
    const unsigned short* __restrict__ W1T, const float* __restrict__ b1,
    const float* __restrict__ w2, const float* __restrict__ tgtv,
    float* __restrict__ out)
{
  const int b = blockIdx.x;
  const int tid = threadIdx.x;
  const int lane = tid & 63;
  const int wave = tid >> 6;
  const int l15 = lane & 15;
  const int lhi = lane >> 4;

  __shared__ __align__(16) unsigned short inp_lds[64 * 256];  // bf16, 16B-granule XOR swizzle
  __shared__ __align__(16) float tgt_lds[TWOD];
  __shared__ float dot_lds[64];
  __shared__ float score_parts[4][64];

  if (tid < 64) {
    ((f32x4*)tgt_lds)[tid] = ((const f32x4*)(tgtv + (size_t)b * TWOD))[tid];
  }
  __syncthreads();

  const int tgt_item = target[b];
  float acc_e = 0.f, acc_ed = 0.f;  // per-lane (wave 0) partials across chunks

  for (int chunk = 0; chunk < 4; ++chunk) {
    // ---- build tile: 64 rows x 256 cols, 8 lanes per row, 2 passes of 32 rows ----
    #pragma unroll
    for (int pass = 0; pass < 2; ++pass) {
      const int row = pass * 32 + (tid >> 3);
      const int j = tid & 7;
      const int hg = chunk * 64 + row;
      const int item = history[b * NH + hg];
      const int regi = hregion[b * NH + hg];
      const float* eh = E_hist + (size_t)item * EMB;
      const float* er = E_reg + (size_t)regi * EMB;
      float dsum = 0.f;
      #pragma unroll
      for (int s = 0; s < 4; ++s) {
        const int col = j * 8 + s * 64;  // 0..255, 8 contiguous floats
        const float* src = (col < EMB) ? (eh + col) : (er + (col - EMB));
        f32x4 v0 = ((const f32x4*)src)[0];
        f32x4 v1 = ((const f32x4*)src)[1];
        f32x4 t0 = ((const f32x4*)(tgt_lds + col))[0];
        f32x4 t1 = ((const f32x4*)(tgt_lds + col))[1];
        v0 *= t0; v1 *= t1;
        dsum += v0[0] + v0[1] + v0[2] + v0[3] + v1[0] + v1[1] + v1[2] + v1[3];
        bf16x8 w;
        w[0] = (short)f2bf(v0[0]); w[1] = (short)f2bf(v0[1]);
        w[2] = (short)f2bf(v0[2]); w[3] = (short)f2bf(v0[3]);
        w[4] = (short)f2bf(v1[0]); w[5] = (short)f2bf(v1[1]);
        w[6] = (short)f2bf(v1[2]); w[7] = (short)f2bf(v1[3]);
        const int g = (j + s * 8) ^ (row & 7);  // 16B-granule swizzle
        *(bf16x8*)(&inp_lds[row * 256 + g * 8]) = w;
      }
      // dot_ht = row-sum of inp (fp32, pre-quantization)
      dsum += __shfl_xor(dsum, 1);
      dsum += __shfl_xor(dsum, 2);
      dsum += __shfl_xor(dsum, 4);
      if (j == 0) dot_lds[row] = dsum;
    }
    __syncthreads();

    // ---- GEMM: this wave's 64x64 strip, K = 256 in 8 steps of 32 ----
    f32x4 acc[4][4];
    #pragma unroll
    for (int m = 0; m < 4; ++m)
      #pragma unroll
      for (int n = 0; n < 4; ++n)
        acc[m][n] = (f32x4){0.f, 0.f, 0.f, 0.f};

    #pragma unroll
    for (int kk = 0; kk < 8; ++kk) {
      bf16x8 af[4], bfr[4];
      #pragma unroll
      for (int m = 0; m < 4; ++m) {
        const int row = m * 16 + l15;
        const int g = (kk * 4 + lhi) ^ (row & 7);
        af[m] = *(const bf16x8*)(&inp_lds[row * 256 + g * 8]);
      }
      #pragma unroll
      for (int n = 0; n < 4; ++n) {
        const int colh = wave * 64 + n * 16 + l15;
        bfr[n] = *(const bf16x8*)(W1T + (size_t)colh * TWOD + kk * 32 + lhi * 8);
      }
      #pragma unroll
      for (int m = 0; m < 4; ++m)
        #pragma unroll
        for (int n = 0; n < 4; ++n)
          acc[m][n] = __builtin_amdgcn_mfma_f32_16x16x32_bf16(af[m], bfr[n], acc[m][n], 0, 0, 0);
    }

    // ---- epilogue: relu + b1, dot with w2, reduce over this wave's 64 cols ----
    float b1v[4], w2v[4];
    #pragma unroll
    for (int n = 0; n < 4; ++n) {
      const int colh = wave * 64 + n * 16 + l15;
      b1v[n] = b1[colh];
      w2v[n] = w2[colh];
    }
    #pragma unroll
    for (int m = 0; m < 4; ++m) {
      #pragma unroll
      for (int r = 0; r < 4; ++r) {
        float p = 0.f;
        #pragma unroll
        for (int n = 0; n < 4; ++n) {
          float hv = acc[m][n][r] + b1v[n];  // C/D: col=lane&15, row=(lane>>4)*4+reg
          hv = hv > 0.f ? hv : 0.f;
          p += hv * w2v[n];
        }
        p += __shfl_xor(p, 1);
        p += __shfl_xor(p, 2);
        p += __shfl_xor(p, 4);
        p += __shfl_xor(p, 8);
        if (l15 == 0) score_parts[wave][m * 16 + lhi * 4 + r] = p;
      }
    }
    __syncthreads();

    if (wave == 0) {
      const int hg = chunk * 64 + lane;
      const float sc = score_parts[0][lane] + score_parts[1][lane] +
                       score_parts[2][lane] + score_parts[3][lane];
      const float e = (history[b * NH + hg] != tgt_item) ? expf(sc) : 0.f;
      acc_e += e;
      acc_ed += e * dot_lds[lane];
    }
    __syncthreads();  // protect dot_lds/score_parts/inp_lds before next chunk
  }

  if (wave == 0) {
    float se = acc_e, sd = acc_ed;
    #pragma unroll
    for (int off = 32; off >= 1; off >>= 1) {
      se += __shfl_xor(se, off);
      sd += __shfl_xor(sd, off);
    }
    if (lane == 0) {
      const float pred = (se > 0.f) ? (sd / sqrtf(se)) : 0.f;  // denom = sum^0.5
      out[b] = 1.f / (1.f + expf(-pred));
    }
  }
}

extern "C" void kernel_launch(void* const* d_in, const int* in_sizes, int n_in,
                              void* d_out, int out_size, void* d_ws, size_t ws_size,
                              hipStream_t stream) {
  const int* history = (const int*)d_in[0];
  const int* target  = (const int*)d_in[1];
  const int* hregion = (const int*)d_in[2];
  const int* tregion = (const int*)d_in[3];
  const float* E_hist = (const float*)d_in[4];
  const float* E_targ = (const float*)d_in[5];
  const float* E_reg  = (const float*)d_in[6];
  const float* W1 = (const float*)d_in[7];
  const float* b1 = (const float*)d_in[8];
  const float* w2 = (const float*)d_in[9];
  float* out = (float*)d_out;

  unsigned short* W1T = (unsigned short*)d_ws;
  float* tgtv = (float*)((char*)d_ws + (size_t)TWOD * HID * sizeof(unsigned short));

  prep_w1t<<<TWOD, HID, 0, stream>>>(W1, W1T);
  prep_tgt<<<NB, TWOD, 0, stream>>>(target, tregion, E_targ, E_reg, tgtv);
  nais_main<<<NB, 256, 0, stream>>>(history, target, hregion, E_hist, E_reg,
                                    W1T, b1, w2, tgtv, out);
}

// Round 2
// 123.375 us; speedup vs baseline: 1.0874x; 1.0874x over previous
//
#include <hip/hip_runtime.h>
#include <hip/hip_bf16.h>

#define NB 1024
#define NH 256
#define EMB 128
#define TWOD 256
#define HID 256

typedef __attribute__((ext_vector_type(4))) float f32x4;
typedef __attribute__((ext_vector_type(8))) short bf16x8;

__device__ __forceinline__ unsigned short f2bf(float f) {
  union { float f; unsigned u; } v; v.f = f;
  unsigned u = v.u;
  unsigned r = (u + 0x7fffu + ((u >> 16) & 1u)) >> 16;
  return (unsigned short)r;
}

// W1 [d=256][n=256] fp32 -> W1T [n][d] bf16 (B-fragment: n-major, k contiguous)
__global__ __launch_bounds__(256) void prep_w1t(const float* __restrict__ W1,
                                                unsigned short* __restrict__ W1T) {
  const int d = blockIdx.x;
  const int n = threadIdx.x;
  W1T[(size_t)n * TWOD + d] = f2bf(W1[(size_t)d * HID + n]);
}

// tgtv[b][0..255] = concat(E_targ[target[b]], E_reg[tregion[b]])
__global__ __launch_bounds__(256) void prep_tgt(const int* __restrict__ target,
                                                const int* __restrict__ tregion,
                                                const float* __restrict__ E_targ,
                                                const float* __restrict__ E_reg,
                                                float* __restrict__ tgtv) {
  const int b = blockIdx.x;
  const int c = threadIdx.x;
  float v = (c < EMB) ? E_targ[(size_t)target[b] * EMB + c]
                      : E_reg[(size_t)tregion[b] * EMB + (c - EMB)];
  tgtv[(size_t)b * TWOD + c] = v;
}

// One block (512 threads = 8 waves) per batch element.
// Phase 1: build full 256x256 bf16 inp tile in LDS (swizzled) + row sums + item ids.
// Phase 2: each wave holds its 32-col W1T strip in regs (bfr[8][2], loaded once);
//          4 chunks of 64 rows: ds_read A-frags + 64 MFMA + fused relu/b1/w2 epilogue
//          into score_parts[wave][] — no barriers inside.
// Phase 3: masked exp, denom^0.5, numerator (uses precomputed row sums), sigmoid.
__global__ __launch_bounds__(512, 2) void nais_main(
    const int* __restrict__ history, const int* __restrict__ target,
    const int* __restrict__ hregion,
    const float* __restrict__ E_hist, const float* __restrict__ E_reg,
    const unsigned short* __restrict__ W1T, const float* __restrict__ b1,
    const float* __restrict__ w2, const float* __restrict__ tgtv,
    float* __restrict__ out)
{
  const int b = blockIdx.x;
  const int tid = threadIdx.x;
  const int lane = tid & 63;
  const int wave = tid >> 6;      // 0..7
  const int l15 = lane & 15;
  const int lhi = lane >> 4;

  __shared__ __align__(16) unsigned short inp_lds[256 * 256];  // 128 KiB, swizzled
  __shared__ __align__(16) float tgt_lds[TWOD];
  __shared__ float dot_lds[256];
  __shared__ int items_lds[256];
  __shared__ float score_parts[8][256];
  __shared__ float part_e[4], part_ed[4];

  if (tid < 64) {
    ((f32x4*)tgt_lds)[tid] = ((const f32x4*)(tgtv + (size_t)b * TWOD))[tid];
  }
  const int tgt_item = target[b];
  __syncthreads();

  // ---- Phase 1: build the full tile. thread -> (row = tid>>1, half = tid&1) ----
  {
    const int row = tid >> 1;
    const int half = tid & 1;      // half 0: cols 0..127 (E_hist), half 1: 128..255 (E_reg)
    const int item = history[b * NH + row];
    const int regi = hregion[b * NH + row];
    if (half == 0) items_lds[row] = item;
    const float* src_base = half ? (E_reg + (size_t)regi * EMB)
                                 : (E_hist + (size_t)item * EMB);
    const float* tgt_base = tgt_lds + half * EMB;
    float dsum = 0.f;
    #pragma unroll
    for (int s = 0; s < 16; ++s) {
      f32x4 v0 = ((const f32x4*)(src_base + s * 8))[0];
      f32x4 v1 = ((const f32x4*)(src_base + s * 8))[1];
      f32x4 t0 = ((const f32x4*)(tgt_base + s * 8))[0];
      f32x4 t1 = ((const f32x4*)(tgt_base + s * 8))[1];
      v0 *= t0; v1 *= t1;
      dsum += v0[0] + v0[1] + v0[2] + v0[3] + v1[0] + v1[1] + v1[2] + v1[3];
      bf16x8 w;
      w[0] = (short)f2bf(v0[0]); w[1] = (short)f2bf(v0[1]);
      w[2] = (short)f2bf(v0[2]); w[3] = (short)f2bf(v0[3]);
      w[4] = (short)f2bf(v1[0]); w[5] = (short)f2bf(v1[1]);
      w[6] = (short)f2bf(v1[2]); w[7] = (short)f2bf(v1[3]);
      const int gi = half * 16 + s;                 // granule 0..31 within row
      const int g = gi ^ (row & 7);                 // 16B-granule XOR swizzle
      *(bf16x8*)(&inp_lds[row * 256 + g * 8]) = w;
    }
    dsum += __shfl_xor(dsum, 1);                    // combine the two halves
    if (half == 0) dot_lds[row] = dsum;
  }
  __syncthreads();

  // ---- Phase 2: GEMM. wave owns cols [wave*32, wave*32+32) ----
  bf16x8 bfr[8][2];
  float b1v[2], w2v[2];
  #pragma unroll
  for (int n = 0; n < 2; ++n) {
    const int colh = wave * 32 + n * 16 + l15;
    b1v[n] = b1[colh];
    w2v[n] = w2[colh];
    #pragma unroll
    for (int kk = 0; kk < 8; ++kk)
      bfr[kk][n] = *(const bf16x8*)(W1T + (size_t)colh * TWOD + kk * 32 + lhi * 8);
  }

  #pragma unroll
  for (int c = 0; c < 4; ++c) {
    f32x4 acc[4][2];
    #pragma unroll
    for (int m = 0; m < 4; ++m)
      #pragma unroll
      for (int n = 0; n < 2; ++n)
        acc[m][n] = (f32x4){0.f, 0.f, 0.f, 0.f};

    #pragma unroll
    for (int kk = 0; kk < 8; ++kk) {
      bf16x8 af[4];
      #pragma unroll
      for (int m = 0; m < 4; ++m) {
        const int row = c * 64 + m * 16 + l15;
        const int g = (kk * 4 + lhi) ^ (row & 7);
        af[m] = *(const bf16x8*)(&inp_lds[row * 256 + g * 8]);
      }
      #pragma unroll
      for (int m = 0; m < 4; ++m)
        #pragma unroll
        for (int n = 0; n < 2; ++n)
          acc[m][n] = __builtin_amdgcn_mfma_f32_16x16x32_bf16(af[m], bfr[kk][n], acc[m][n], 0, 0, 0);
    }

    // epilogue: relu + b1, dot with w2, reduce 32 cols -> score_parts[wave][row]
    #pragma unroll
    for (int m = 0; m < 4; ++m) {
      #pragma unroll
      for (int r = 0; r < 4; ++r) {
        float p = 0.f;
        #pragma unroll
        for (int n = 0; n < 2; ++n) {
          float hv = acc[m][n][r] + b1v[n];   // C/D: col=lane&15, row=(lane>>4)*4+r
          hv = hv > 0.f ? hv : 0.f;
          p += hv * w2v[n];
        }
        p += __shfl_xor(p, 1);
        p += __shfl_xor(p, 2);
        p += __shfl_xor(p, 4);
        p += __shfl_xor(p, 8);
        if (l15 == 0) score_parts[wave][c * 64 + m * 16 + lhi * 4 + r] = p;
      }
    }
  }
  __syncthreads();

  // ---- Phase 3: softmax-ish reduction + output ----
  if (wave < 4) {
    const int row = wave * 64 + lane;
    float sc = 0.f;
    #pragma unroll
    for (int w = 0; w < 8; ++w) sc += score_parts[w][row];
    const float e = (items_lds[row] != tgt_item) ? expf(sc) : 0.f;
    float ed = e * dot_lds[row];
    float se = e;
    #pragma unroll
    for (int off = 32; off >= 1; off >>= 1) {
      se += __shfl_xor(se, off);
      ed += __shfl_xor(ed, off);
    }
    if (lane == 0) { part_e[wave] = se; part_ed[wave] = ed; }
  }
  __syncthreads();

  if (tid == 0) {
    const float se = part_e[0] + part_e[1] + part_e[2] + part_e[3];
    const float sd = part_ed[0] + part_ed[1] + part_ed[2] + part_ed[3];
    const float pred = (se > 0.f) ? (sd / sqrtf(se)) : 0.f;  // denom = sum^0.5
    out[b] = 1.f / (1.f + expf(-pred));
  }
}

extern "C" void kernel_launch(void* const* d_in, const int* in_sizes, int n_in,
                              void* d_out, int out_size, void* d_ws, size_t ws_size,
                              hipStream_t stream) {
  const int* history = (const int*)d_in[0];
  const int* target  = (const int*)d_in[1];
  const int* hregion = (const int*)d_in[2];
  const int* tregion = (const int*)d_in[3];
  const float* E_hist = (const float*)d_in[4];
  const float* E_targ = (const float*)d_in[5];
  const float* E_reg  = (const float*)d_in[6];
  const float* W1 = (const float*)d_in[7];
  const float* b1 = (const float*)d_in[8];
  const float* w2 = (const float*)d_in[9];
  float* out = (float*)d_out;

  unsigned short* W1T = (unsigned short*)d_ws;
  float* tgtv = (float*)((char*)d_ws + (size_t)TWOD * HID * sizeof(unsigned short));

  prep_w1t<<<TWOD, HID, 0, stream>>>(W1, W1T);
  prep_tgt<<<NB, TWOD, 0, stream>>>(target, tregion, E_targ, E_reg, tgtv);
  nais_main<<<NB, 512, 0, stream>>>(history, target, hregion, E_hist, E_reg,
                                    W1T, b1, w2, tgtv, out);
}

// Round 3
// 96.342 us; speedup vs baseline: 1.3925x; 1.2806x over previous
//
#include <hip/hip_runtime.h>
#include <hip/hip_bf16.h>

#define NB 1024
#define NH 256
#define EMB 128
#define TWOD 256
#define HID 256
#define ROWS 128            // history rows per block
#define NBLK (NB * 2)       // 2 blocks per batch element

typedef __attribute__((ext_vector_type(4))) float f32x4;
typedef __attribute__((ext_vector_type(8))) short bf16x8;

__device__ __forceinline__ unsigned short f2bf(float f) {
  union { float f; unsigned u; } v; v.f = f;
  unsigned u = v.u;
  unsigned r = (u + 0x7fffu + ((u >> 16) & 1u)) >> 16;
  return (unsigned short)r;
}

// W1 [d=256][n=256] fp32 -> W1T [n][d] bf16 (B-fragment: n-major, k contiguous)
__global__ __launch_bounds__(256) void prep_w1t(const float* __restrict__ W1,
                                                unsigned short* __restrict__ W1T) {
  const int d = blockIdx.x;
  const int n = threadIdx.x;
  W1T[(size_t)n * TWOD + d] = f2bf(W1[(size_t)d * HID + n]);
}

// tgtv[b][0..255] = concat(E_targ[target[b]], E_reg[tregion[b]])
__global__ __launch_bounds__(256) void prep_tgt(const int* __restrict__ target,
                                                const int* __restrict__ tregion,
                                                const float* __restrict__ E_targ,
                                                const float* __restrict__ E_reg,
                                                float* __restrict__ tgtv) {
  const int b = blockIdx.x;
  const int c = threadIdx.x;
  float v = (c < EMB) ? E_targ[(size_t)target[b] * EMB + c]
                      : E_reg[(size_t)tregion[b] * EMB + (c - EMB)];
  tgtv[(size_t)b * TWOD + c] = v;
}

__global__ __launch_bounds__(256) void zero_acc(float* __restrict__ p) {
  p[blockIdx.x * 256 + threadIdx.x] = 0.f;
}

// 2048 blocks (2 per batch element), 512 threads = 8 waves, 128 rows per block.
// Gather: wave-cooperative, fully coalesced — lanes 0..31 read one contiguous
// E_hist row (512B), lanes 32..63 the matching E_reg row. 16 rows per wave,
// keys + row data prefetched into register arrays (deep MLP).
// GEMM: wave owns a 32-col W1T strip in regs; 2 chunks of 64 rows, fused
// relu/b1/w2 epilogue. Partial (sum e, sum e*dot) -> global atomics.
__global__ __launch_bounds__(512, 4) void nais_main(
    const int* __restrict__ history, const int* __restrict__ target,
    const int* __restrict__ hregion,
    const float* __restrict__ E_hist, const float* __restrict__ E_reg,
    const unsigned short* __restrict__ W1T, const float* __restrict__ b1,
    const float* __restrict__ w2, const float* __restrict__ tgtv,
    float* __restrict__ acc_se, float* __restrict__ acc_sd)
{
  const int blk = blockIdx.x;
  const int b = blk >> 1;
  const int r0 = (blk & 1) * ROWS;      // row offset within the 256-history
  const int tid = threadIdx.x;
  const int lane = tid & 63;
  const int wave = tid >> 6;            // 0..7
  const int l15 = lane & 15;
  const int lhi = lane >> 4;
  const int l31 = lane & 31;
  const int halfsel = lane >> 5;        // 0: E_hist half, 1: E_reg half

  __shared__ __align__(16) unsigned short inp_lds[ROWS * 256];  // 64 KiB, swizzled
  __shared__ float dot_lds[ROWS];
  __shared__ float score_parts[8][ROWS];

  const int tgt_item = target[b];

  // ---- Phase 1: coalesced gather + multiply + bf16 tile + row sums ----
  {
    // my 4 target cols (col = halfsel*128 + l31*4), constant across rows
    const f32x4 t = *(const f32x4*)(tgtv + (size_t)b * TWOD + halfsel * EMB + l31 * 4);
    const int* keysrc = halfsel ? hregion : history;
    const float* table = halfsel ? E_reg : E_hist;

    int key[16];
    #pragma unroll
    for (int s = 0; s < 16; ++s)
      key[s] = keysrc[b * NH + r0 + wave * 16 + s];

    f32x4 vb[16];
    #pragma unroll
    for (int s = 0; s < 16; ++s)
      vb[s] = *(const f32x4*)(table + (size_t)key[s] * EMB + l31 * 4);

    #pragma unroll
    for (int s = 0; s < 16; ++s) {
      const int row = wave * 16 + s;
      f32x4 v = vb[s] * t;
      float ds = v[0] + v[1] + v[2] + v[3];
      ds += __shfl_xor(ds, 1);
      ds += __shfl_xor(ds, 2);
      ds += __shfl_xor(ds, 4);
      ds += __shfl_xor(ds, 8);
      ds += __shfl_xor(ds, 16);
      ds += __shfl_xor(ds, 32);         // combine E_hist + E_reg halves
      if (lane == 0) dot_lds[row] = ds;

      float2 f01; f01.x = v[0]; f01.y = v[1];
      float2 f23; f23.x = v[2]; f23.y = v[3];
      __hip_bfloat162 p0 = __float22bfloat162_rn(f01);
      __hip_bfloat162 p1 = __float22bfloat162_rn(f23);
      union { __hip_bfloat162 h; unsigned u; } c0, c1;
      c0.h = p0; c1.h = p1;
      const int g = halfsel * 16 + (l31 >> 1);          // 16B granule 0..31
      const int gs = g ^ (row & 7) ^ ((g >> 3) & 3);    // swizzle (bijective/row)
      unsigned* dst = (unsigned*)&inp_lds[row * 256 + gs * 8 + (lane & 1) * 4];
      dst[0] = c0.u; dst[1] = c1.u;
    }
  }
  __syncthreads();

  // ---- Phase 2: GEMM. wave owns cols [wave*32, wave*32+32) ----
  bf16x8 bfr[8][2];
  float b1v[2], w2v[2];
  #pragma unroll
  for (int n = 0; n < 2; ++n) {
    const int colh = wave * 32 + n * 16 + l15;
    b1v[n] = b1[colh];
    w2v[n] = w2[colh];
    #pragma unroll
    for (int kk = 0; kk < 8; ++kk)
      bfr[kk][n] = *(const bf16x8*)(W1T + (size_t)colh * TWOD + kk * 32 + lhi * 8);
  }

  #pragma unroll
  for (int c = 0; c < 2; ++c) {
    f32x4 acc[4][2];
    #pragma unroll
    for (int m = 0; m < 4; ++m)
      #pragma unroll
      for (int n = 0; n < 2; ++n)
        acc[m][n] = (f32x4){0.f, 0.f, 0.f, 0.f};

    #pragma unroll
    for (int kk = 0; kk < 8; ++kk) {
      bf16x8 af[4];
      #pragma unroll
      for (int m = 0; m < 4; ++m) {
        const int row = c * 64 + m * 16 + l15;
        const int gk = kk * 4 + lhi;
        const int gs = gk ^ (row & 7) ^ ((gk >> 3) & 3);
        af[m] = *(const bf16x8*)(&inp_lds[row * 256 + gs * 8]);
      }
      #pragma unroll
      for (int m = 0; m < 4; ++m)
        #pragma unroll
        for (int n = 0; n < 2; ++n)
          acc[m][n] = __builtin_amdgcn_mfma_f32_16x16x32_bf16(af[m], bfr[kk][n], acc[m][n], 0, 0, 0);
    }

    // epilogue: relu + b1, dot with w2, reduce 32 cols -> score_parts[wave][row]
    #pragma unroll
    for (int m = 0; m < 4; ++m) {
      #pragma unroll
      for (int r = 0; r < 4; ++r) {
        float p = 0.f;
        #pragma unroll
        for (int n = 0; n < 2; ++n) {
          float hv = acc[m][n][r] + b1v[n];   // C/D: col=lane&15, row=(lane>>4)*4+r
          hv = hv > 0.f ? hv : 0.f;
          p += hv * w2v[n];
        }
        p += __shfl_xor(p, 1);
        p += __shfl_xor(p, 2);
        p += __shfl_xor(p, 4);
        p += __shfl_xor(p, 8);
        if (l15 == 0) score_parts[wave][c * 64 + m * 16 + lhi * 4 + r] = p;
      }
    }
  }
  __syncthreads();

  // ---- Phase 3: masked exp + partial sums -> global atomics ----
  if (wave < 2) {
    const int lrow = wave * 64 + lane;
    float sc = 0.f;
    #pragma unroll
    for (int w = 0; w < 8; ++w) sc += score_parts[w][lrow];
    const int item = history[b * NH + r0 + lrow];
    float e = (item != tgt_item) ? expf(sc) : 0.f;
    float ed = e * dot_lds[lrow];
    #pragma unroll
    for (int off = 32; off >= 1; off >>= 1) {
      e += __shfl_xor(e, off);
      ed += __shfl_xor(ed, off);
    }
    if (lane == 0) {
      atomicAdd(&acc_se[b], e);
      atomicAdd(&acc_sd[b], ed);
    }
  }
}

__global__ __launch_bounds__(256) void finalize(const float* __restrict__ acc_se,
                                                const float* __restrict__ acc_sd,
                                                float* __restrict__ out) {
  const int b = blockIdx.x * 256 + threadIdx.x;
  if (b < NB) {
    const float se = acc_se[b];
    const float sd = acc_sd[b];
    const float pred = (se > 0.f) ? (sd / sqrtf(se)) : 0.f;  // denom = sum^0.5
    out[b] = 1.f / (1.f + expf(-pred));
  }
}

extern "C" void kernel_launch(void* const* d_in, const int* in_sizes, int n_in,
                              void* d_out, int out_size, void* d_ws, size_t ws_size,
                              hipStream_t stream) {
  const int* history = (const int*)d_in[0];
  const int* target  = (const int*)d_in[1];
  const int* hregion = (const int*)d_in[2];
  const int* tregion = (const int*)d_in[3];
  const float* E_hist = (const float*)d_in[4];
  const float* E_targ = (const float*)d_in[5];
  const float* E_reg  = (const float*)d_in[6];
  const float* W1 = (const float*)d_in[7];
  const float* b1 = (const float*)d_in[8];
  const float* w2 = (const float*)d_in[9];
  float* out = (float*)d_out;

  unsigned short* W1T = (unsigned short*)d_ws;
  char* p = (char*)d_ws + (size_t)TWOD * HID * sizeof(unsigned short);
  float* tgtv = (float*)p;           p += (size_t)NB * TWOD * sizeof(float);
  float* acc_se = (float*)p;         p += (size_t)NB * sizeof(float);
  float* acc_sd = (float*)p;

  zero_acc<<<(2 * NB) / 256, 256, 0, stream>>>(acc_se);   // zeroes se+sd (contiguous)
  prep_w1t<<<TWOD, HID, 0, stream>>>(W1, W1T);
  prep_tgt<<<NB, TWOD, 0, stream>>>(target, tregion, E_targ, E_reg, tgtv);
  nais_main<<<NBLK, 512, 0, stream>>>(history, target, hregion, E_hist, E_reg,
                                      W1T, b1, w2, tgtv, acc_se, acc_sd);
  finalize<<<(NB + 255) / 256, 256, 0, stream>>>(acc_se, acc_sd, out);
}